// Round 19
// baseline (153.598 us; speedup 1.0000x reference)
//
#include <hip/hip_runtime.h>
#include <math.h>

#define NTHREADS 256
#define MAXBLOCKS 2048
#define UNROLL 8

// Adaptive Wing loss, fused elementwise + partial reduction.
// THETA=0.5, ALPHA=2.1, W=14, E=1.
//   expo = 2.1 - y ; p = exp2(-expo) ; A = 28*expo*p/(1+p)
//   loss_large = A*(diff-0.5) + 14*log1p(p) ; loss_small = 14*log1p(diff^expo)
// Ladder: 133us (libm, VALU-bound) -> 44us (HW trans, R13) -> 43us (R15/R17:
// source batching AND sched_barrier(0) both undone by compiler, VGPR stuck
// at 24 => ~2 loads in flight, VALUBusy 23%, HBM 19%, latency-bound).
// R18: inline-asm global_load_dwordx4 (SGPR base + VGPR byte-offset), 16
// ordered volatile loads, then staged s_waitcnt vmcnt(14..0) each carrying
// the consumed pair as "+v" operands so compute cannot hoist above its wait.
// Volatile asm cannot be sunk/re-rolled -> MLP finally enforced (~16KB
// in flight per wave at issue vs 2KB before).
// diff==0 edge: v_log(0)=-inf -> exp2(-inf)=0 -> log2(1)=0. Correct limit.

#define W_LN2F 9.70406052783923f   // 14*ln2

typedef float f32x4 __attribute__((ext_vector_type(4)));

__device__ __forceinline__ float awing_elem(float xv, float yv) {
    float expo  = 2.1f - yv;
    float p     = __builtin_amdgcn_exp2f(-expo);
    float l2_1p = __builtin_amdgcn_logf(1.0f + p);      // log2(1+p)
    float A     = 28.0f * expo * p * __builtin_amdgcn_rcpf(1.0f + p);
    float diff  = fabsf(yv - xv);
    // diff^expo = exp2(expo * log2(diff))
    float t     = __builtin_amdgcn_exp2f(expo * __builtin_amdgcn_logf(diff));
    float lsml  = W_LN2F * __builtin_amdgcn_logf(1.0f + t);
    float llrg  = fmaf(A, diff - 0.5f, W_LN2F * l2_1p);
    return (diff < 0.5f) ? lsml : llrg;
}

// Issue one 16B load from sgpr-base + vgpr byte offset. Volatile: cannot be
// sunk by any pass. Dest is written at completion; waitcnt below fences use.
#define GLOAD(dst, boff, base) \
    asm volatile("global_load_dwordx4 %0, %1, %2" : "=v"(dst) : "v"(boff), "s"(base))

// Staged wait: allow CNT outstanding vmem ops, then fence the pair (xu,yu)
// via "+v" so their consumers cannot be scheduled above this point.
#define PWAIT(CNT, XN, YN) \
    asm volatile("s_waitcnt vmcnt(" #CNT ")" : "+v"(XN), "+v"(YN))

#define PCOMP(XN, YN) \
    acc += awing_elem(XN.x, YN.x); \
    acc += awing_elem(XN.y, YN.y); \
    acc += awing_elem(XN.z, YN.z); \
    acc += awing_elem(XN.w, YN.w)

__global__ __launch_bounds__(NTHREADS, 4) void awing_partial_kernel(
    const float* __restrict__ inp, const float* __restrict__ tgt,
    float* __restrict__ partial, int n)
{
    const int tid    = blockIdx.x * blockDim.x + threadIdx.x;
    const int stride = gridDim.x * blockDim.x;
    const int n4     = n >> 2;

    const float4* __restrict__ in4 = (const float4*)inp;
    const float4* __restrict__ tg4 = (const float4*)tgt;

    float acc = 0.0f;
    int i = tid;

    // Main path: 8 strided float4-pairs, all 16 loads in flight via asm.
    for (; i + (UNROLL - 1) * stride < n4; i += UNROLL * stride) {
        unsigned o0 = ((unsigned)(i             )) << 4;
        unsigned o1 = ((unsigned)(i + 1 * stride)) << 4;
        unsigned o2 = ((unsigned)(i + 2 * stride)) << 4;
        unsigned o3 = ((unsigned)(i + 3 * stride)) << 4;
        unsigned o4 = ((unsigned)(i + 4 * stride)) << 4;
        unsigned o5 = ((unsigned)(i + 5 * stride)) << 4;
        unsigned o6 = ((unsigned)(i + 6 * stride)) << 4;
        unsigned o7 = ((unsigned)(i + 7 * stride)) << 4;

        f32x4 x0, x1, x2, x3, x4, x5, x6, x7;
        f32x4 y0, y1, y2, y3, y4, y5, y6, y7;

        // Issue order: (x0,y0),(x1,y1),... so staged vmcnt drains pairwise.
        GLOAD(x0, o0, in4); GLOAD(y0, o0, tg4);
        GLOAD(x1, o1, in4); GLOAD(y1, o1, tg4);
        GLOAD(x2, o2, in4); GLOAD(y2, o2, tg4);
        GLOAD(x3, o3, in4); GLOAD(y3, o3, tg4);
        GLOAD(x4, o4, in4); GLOAD(y4, o4, tg4);
        GLOAD(x5, o5, in4); GLOAD(y5, o5, tg4);
        GLOAD(x6, o6, in4); GLOAD(y6, o6, tg4);
        GLOAD(x7, o7, in4); GLOAD(y7, o7, tg4);

        PWAIT(14, x0, y0); PCOMP(x0, y0);
        PWAIT(12, x1, y1); PCOMP(x1, y1);
        PWAIT(10, x2, y2); PCOMP(x2, y2);
        PWAIT( 8, x3, y3); PCOMP(x3, y3);
        PWAIT( 6, x4, y4); PCOMP(x4, y4);
        PWAIT( 4, x5, y5); PCOMP(x5, y5);
        PWAIT( 2, x6, y6); PCOMP(x6, y6);
        PWAIT( 0, x7, y7); PCOMP(x7, y7);
    }
    // Strided remainder (n4 not divisible by UNROLL*stride) — plain path.
    for (; i < n4; i += stride) {
        float4 x = in4[i];
        float4 y = tg4[i];
        acc += awing_elem(x.x, y.x);
        acc += awing_elem(x.y, y.y);
        acc += awing_elem(x.z, y.z);
        acc += awing_elem(x.w, y.w);
    }
    // scalar tail (n % 4 != 0)
    for (int j = (n4 << 2) + tid; j < n; j += stride) {
        acc += awing_elem(inp[j], tgt[j]);
    }

    // wave-64 butterfly reduce
    #pragma unroll
    for (int off = 32; off > 0; off >>= 1)
        acc += __shfl_down(acc, off, 64);

    __shared__ float sacc[NTHREADS / 64];
    const int lane = threadIdx.x & 63;
    const int wid  = threadIdx.x >> 6;
    if (lane == 0) sacc[wid] = acc;
    __syncthreads();
    if (threadIdx.x == 0) {
        float s = 0.0f;
        #pragma unroll
        for (int w = 0; w < NTHREADS / 64; ++w) s += sacc[w];
        partial[blockIdx.x] = s;
    }
}

__global__ __launch_bounds__(NTHREADS) void awing_final_kernel(
    const float* __restrict__ partial, float* __restrict__ out, int nparts)
{
    float acc = 0.0f;
    for (int i = threadIdx.x; i < nparts; i += NTHREADS)
        acc += partial[i];

    #pragma unroll
    for (int off = 32; off > 0; off >>= 1)
        acc += __shfl_down(acc, off, 64);

    __shared__ float sacc[NTHREADS / 64];
    const int lane = threadIdx.x & 63;
    const int wid  = threadIdx.x >> 6;
    if (lane == 0) sacc[wid] = acc;
    __syncthreads();
    if (threadIdx.x == 0) {
        float s = 0.0f;
        #pragma unroll
        for (int w = 0; w < NTHREADS / 64; ++w) s += sacc[w];
        out[0] = s;
    }
}

extern "C" void kernel_launch(void* const* d_in, const int* in_sizes, int n_in,
                              void* d_out, int out_size, void* d_ws, size_t ws_size,
                              hipStream_t stream) {
    const float* inp = (const float*)d_in[0];
    const float* tgt = (const float*)d_in[1];
    float* out       = (float*)d_out;
    float* partial   = (float*)d_ws;   // MAXBLOCKS floats = 8 KB scratch

    const int n = in_sizes[0];

    int nblocks = (n / 4 + NTHREADS - 1) / NTHREADS;
    if (nblocks > MAXBLOCKS) nblocks = MAXBLOCKS;
    if (nblocks < 1) nblocks = 1;

    awing_partial_kernel<<<nblocks, NTHREADS, 0, stream>>>(inp, tgt, partial, n);
    awing_final_kernel<<<1, NTHREADS, 0, stream>>>(partial, out, nblocks);
}